// Round 11
// baseline (144.584 us; speedup 1.0000x reference)
//
#include <hip/hip_runtime.h>

#define FDIM 512
#define S_ELEMS (FDIM * FDIM)
#define NB 256
#define GROUPS 2
#define BPG (NB / GROUPS)          // 128 batches per group
#define SLABS 16                   // 32-row slabs per batch
#define GBLK (BPG * SLABS)         // 2048 blocks per K1/K3 dispatch

// ---------------- ws layout (floats) ----------------
#define R_OFF  0                               // r[256][512]
#define C_OFF  (NB * FDIM)                     // c[256][512] (final)
#define S_OFF  (2 * NB * FDIM)                 // s[256]
#define CP_OFF (2 * NB * FDIM + NB)            // c_part[256*16][512]
#define WS_FLOATS (CP_OFF + NB * SLABS * FDIM)

__device__ __forceinline__ float4 ld4(const float* p) { return *(const float4*)p; }

typedef float vf4 __attribute__((ext_vector_type(4)));
__device__ __forceinline__ void st4nt(float* p, float4 v) {
    __builtin_nontemporal_store(*(vf4*)&v, (vf4*)p);
}

// ======================= K1: p, r, c-partials (pure read) ==============
// block = (batch, 32-row slab); 256 thr = 4 waves; 8 rows/wave, 4-deep
// named-register pipeline. 2048 blocks/dispatch -> ~6 blocks/CU.
__global__ __launch_bounds__(256)
void k1_kernel(const float* __restrict__ mu,
               const float* __restrict__ Sigma,
               float* __restrict__ p_out,
               float* __restrict__ ws,
               int b0) {
    const int bid  = blockIdx.x;
    const int b    = b0 + (bid >> 4);
    const int slab = bid & 15;
    const int t = threadIdx.x;
    const int w = t >> 6;
    const int l = t & 63;

    __shared__ __align__(16) float p_lds[FDIM];
    __shared__ __align__(16) float cred[4][FDIM];
    __shared__ float red[4];
    __shared__ float sc1;

    // --- softmax p[b,:], 2 elems/thread ---
    const float x0 = mu[(size_t)b * FDIM + t];
    const float x1 = mu[(size_t)b * FDIM + t + 256];
    float m = fmaxf(x0, x1);
    #pragma unroll
    for (int off = 32; off >= 1; off >>= 1) m = fmaxf(m, __shfl_xor(m, off));
    if (l == 0) red[w] = m;
    __syncthreads();
    if (t == 0) sc1 = fmaxf(fmaxf(red[0], red[1]), fmaxf(red[2], red[3]));
    __syncthreads();
    const float mx = sc1;
    const float e0 = __expf(x0 - mx);
    const float e1 = __expf(x1 - mx);
    float ssum = e0 + e1;
    #pragma unroll
    for (int off = 32; off >= 1; off >>= 1) ssum += __shfl_xor(ssum, off);
    if (l == 0) red[w] = ssum;
    __syncthreads();
    if (t == 0) sc1 = red[0] + red[1] + red[2] + red[3];
    __syncthreads();
    const float inv = 1.0f / sc1;
    const float pva = e0 * inv, pvb = e1 * inv;
    p_lds[t] = pva;
    p_lds[t + 256] = pvb;
    if (slab == 0) {
        p_out[(size_t)b * FDIM + t] = pva;
        p_out[(size_t)b * FDIM + t + 256] = pvb;
    }
    __syncthreads();

    const float4 p0 = ld4(&p_lds[4 * l]);
    const float4 p1 = ld4(&p_lds[256 + 4 * l]);

    const int i0 = slab * 32 + w * 8;
    const float* base = Sigma + (size_t)b * S_ELEMS + (size_t)i0 * FDIM + 4 * l;
    float* r_ws = ws + R_OFF + (size_t)b * FDIM;

    float4 c0 = make_float4(0.f, 0.f, 0.f, 0.f);
    float4 c1 = make_float4(0.f, 0.f, 0.f, 0.f);
    float4 A0, A1, B0, B1, C0, C1, D0, D1;

#define LD1(P, q) do { const float* gp_ = base + (size_t)(q) * FDIM;        \
    P##0 = ld4(gp_); P##1 = ld4(gp_ + 256); } while (0)

#define RCROW(v0, v1, q) do {                                               \
    const int i_ = i0 + (q);                                                \
    float dot = v0.x*p0.x + v0.y*p0.y + v0.z*p0.z + v0.w*p0.w               \
              + v1.x*p1.x + v1.y*p1.y + v1.z*p1.z + v1.w*p1.w;              \
    _Pragma("unroll")                                                       \
    for (int o_ = 32; o_ >= 1; o_ >>= 1) dot += __shfl_xor(dot, o_);        \
    if (l == 0) r_ws[i_] = dot;                                             \
    const float pi_ = p_lds[i_];                                            \
    c0.x += pi_*v0.x; c0.y += pi_*v0.y; c0.z += pi_*v0.z; c0.w += pi_*v0.w; \
    c1.x += pi_*v1.x; c1.y += pi_*v1.y; c1.z += pi_*v1.z; c1.w += pi_*v1.w; \
} while (0)
#define RC1(P, q) RCROW(P##0, P##1, q)

    LD1(A, 0); LD1(B, 1); LD1(C, 2);
    RC1(A, 0); LD1(D, 3);
    RC1(B, 1); LD1(A, 4);
    RC1(C, 2); LD1(B, 5);
    RC1(D, 3); LD1(C, 6);
    RC1(A, 4); LD1(D, 7);
    RC1(B, 5);
    RC1(C, 6);
    RC1(D, 7);
#undef LD1
#undef RCROW
#undef RC1

    // --- reduce c partials across the 4 waves ---
    *(float4*)&cred[w][4 * l] = c0;
    *(float4*)&cred[w][256 + 4 * l] = c1;
    __syncthreads();
    const float ca = cred[0][t] + cred[1][t] + cred[2][t] + cred[3][t];
    const float cb = cred[0][t + 256] + cred[1][t + 256] + cred[2][t + 256] + cred[3][t + 256];
    float* cp = ws + CP_OFF + ((size_t)b * SLABS + slab) * FDIM;
    cp[t] = ca;
    cp[t + 256] = cb;
}

// ======================= K2b: final c + s, per group ===================
__global__ __launch_bounds__(512)
void k2b_kernel(const float* __restrict__ p_out, float* __restrict__ ws, int b0) {
    const int b = b0 + (int)blockIdx.x;
    const int t = threadIdx.x;
    const int w = t >> 6;
    const int l = t & 63;
    __shared__ float red[8];

    float cc = 0.f;
    #pragma unroll
    for (int j = 0; j < SLABS; ++j)
        cc += ws[CP_OFF + ((size_t)b * SLABS + j) * FDIM + t];
    ws[C_OFF + (size_t)b * FDIM + t] = cc;

    float sv = p_out[(size_t)b * FDIM + t] * ws[R_OFF + (size_t)b * FDIM + t];
    #pragma unroll
    for (int off = 32; off >= 1; off >>= 1) sv += __shfl_xor(sv, off);
    if (l == 0) red[w] = sv;
    __syncthreads();
    if (t == 0) {
        float tt = 0.f;
        for (int j = 0; j < 8; ++j) tt += red[j];
        ws[S_OFF + b] = tt;
    }
}

// ======================= K3: output stream (reverse, NT stores) ========
// block = (batch, 32-row slab), reversed within group; 8 rows/wave.
__global__ __launch_bounds__(256)
void k3_kernel(const float* __restrict__ Sigma,
               const float* __restrict__ p_out,
               const float* __restrict__ ws,
               float* __restrict__ S_out,
               int b0) {
    const int bid  = (int)gridDim.x - 1 - (int)blockIdx.x;   // reverse sweep
    const int b    = b0 + (bid >> 4);
    const int slab = bid & 15;
    const int t = threadIdx.x;
    const int w = t >> 6;
    const int l = t & 63;

    __shared__ float pr[32], rr[32];

    const int i0 = slab * 32 + w * 8;
    const float* base = Sigma + (size_t)b * S_ELEMS + (size_t)i0 * FDIM + 4 * l;
    float* obase      = S_out + (size_t)b * S_ELEMS + (size_t)i0 * FDIM + 4 * l;

    float4 A0, A1, B0, B1, C0, C1, D0, D1;

#define LD3(P, q) do { const float* gp_ = base + (size_t)(q) * FDIM;        \
    P##0 = ld4(gp_); P##1 = ld4(gp_ + 256); } while (0)

    // Issue first three row-groups; they fly during the prologue.
    LD3(A, 0); LD3(B, 1); LD3(C, 2);

    const float* pb_g = p_out + (size_t)b * FDIM;
    const float* rb_g = ws + R_OFF + (size_t)b * FDIM;
    if (t < 32) {
        pr[t] = pb_g[slab * 32 + t];
        rr[t] = rb_g[slab * 32 + t];
    }
    const float  s  = ws[S_OFF + b];
    const float4 p0 = ld4(pb_g + 4 * l);
    const float4 p1 = ld4(pb_g + 256 + 4 * l);
    const float4 c0 = ld4(ws + C_OFF + (size_t)b * FDIM + 4 * l);
    const float4 c1 = ld4(ws + C_OFF + (size_t)b * FDIM + 256 + 4 * l);
    __syncthreads();

#define OWROW(v0, v1, q) do {                                               \
    const int lr_ = w * 8 + (q);                                            \
    const float pi_ = pr[lr_];                                              \
    const float f_  = s - rr[lr_];                                          \
    float4 o0, o1;                                                          \
    o0.x = pi_*p0.x*(v0.x + (f_ - c0.x));                                   \
    o0.y = pi_*p0.y*(v0.y + (f_ - c0.y));                                   \
    o0.z = pi_*p0.z*(v0.z + (f_ - c0.z));                                   \
    o0.w = pi_*p0.w*(v0.w + (f_ - c0.w));                                   \
    o1.x = pi_*p1.x*(v1.x + (f_ - c1.x));                                   \
    o1.y = pi_*p1.y*(v1.y + (f_ - c1.y));                                   \
    o1.z = pi_*p1.z*(v1.z + (f_ - c1.z));                                   \
    o1.w = pi_*p1.w*(v1.w + (f_ - c1.w));                                   \
    float* op_ = obase + (size_t)(q) * FDIM;                                \
    st4nt(op_, o0); st4nt(op_ + 256, o1);                                   \
} while (0)
#define OW3(P, q) OWROW(P##0, P##1, q)

    OW3(A, 0); LD3(D, 3);
    OW3(B, 1); LD3(A, 4);
    OW3(C, 2); LD3(B, 5);
    OW3(D, 3); LD3(C, 6);
    OW3(A, 4); LD3(D, 7);
    OW3(B, 5);
    OW3(C, 6);
    OW3(D, 7);
#undef LD3
#undef OWROW
#undef OW3
}

// ======================= fallback: round-1 fused (proven) ========
__global__ __launch_bounds__(1024, 1)
void rvsoftmax_fused(const float* __restrict__ mu,
                     const float* __restrict__ Sigma,
                     float* __restrict__ p_out,
                     float* __restrict__ S_out) {
    const int b = blockIdx.x, t = threadIdx.x, w = t >> 6, l = t & 63;
    __shared__ __align__(16) float p_lds[FDIM];
    __shared__ __align__(16) float r_lds[FDIM];
    __shared__ __align__(16) float c_lds[FDIM];
    __shared__ __align__(16) float c_stage[16][FDIM];
    __shared__ float red[16]; __shared__ float sc[2];
    float x = (t < FDIM) ? mu[(size_t)b * FDIM + t] : -__builtin_inff();
    float m = x;
    #pragma unroll
    for (int off = 32; off >= 1; off >>= 1) m = fmaxf(m, __shfl_xor(m, off));
    if (l == 0) red[w] = m;
    __syncthreads();
    if (t == 0) { float mm = red[0]; for (int j = 1; j < 16; ++j) mm = fmaxf(mm, red[j]); sc[0] = mm; }
    __syncthreads();
    const float mx = sc[0];
    float e = (t < FDIM) ? __expf(x - mx) : 0.f;
    float ssum = e;
    #pragma unroll
    for (int off = 32; off >= 1; off >>= 1) ssum += __shfl_xor(ssum, off);
    if (l == 0) red[w] = ssum;
    __syncthreads();
    if (t == 0) { float tt = 0.f; for (int j = 0; j < 16; ++j) tt += red[j]; sc[0] = tt; }
    __syncthreads();
    const float inv = 1.0f / sc[0];
    if (t < FDIM) { float pv = e * inv; p_lds[t] = pv; p_out[(size_t)b * FDIM + t] = pv; }
    __syncthreads();
    const float* Sb = Sigma + (size_t)b * S_ELEMS;
    const float4 p0 = ld4(&p_lds[4 * l]);
    const float4 p1 = ld4(&p_lds[256 + 4 * l]);
    float4 c0 = make_float4(0.f, 0.f, 0.f, 0.f), c1 = make_float4(0.f, 0.f, 0.f, 0.f);
    for (int j = 0; j < 32; ++j) {
        const int i = j * 16 + w;
        const float* row = Sb + (size_t)i * FDIM;
        const float4 a0 = ld4(&row[4 * l]); const float4 a1 = ld4(&row[256 + 4 * l]);
        const float pi = p_lds[i];
        float dot = a0.x*p0.x + a0.y*p0.y + a0.z*p0.z + a0.w*p0.w
                  + a1.x*p1.x + a1.y*p1.y + a1.z*p1.z + a1.w*p1.w;
        #pragma unroll
        for (int off = 32; off >= 1; off >>= 1) dot += __shfl_xor(dot, off);
        if (l == 0) r_lds[i] = dot;
        c0.x += pi*a0.x; c0.y += pi*a0.y; c0.z += pi*a0.z; c0.w += pi*a0.w;
        c1.x += pi*a1.x; c1.y += pi*a1.y; c1.z += pi*a1.z; c1.w += pi*a1.w;
    }
    *(float4*)&c_stage[w][4 * l] = c0;
    *(float4*)&c_stage[w][256 + 4 * l] = c1;
    __syncthreads();
    if (t < FDIM) {
        float cc = 0.f;
        #pragma unroll
        for (int j = 0; j < 16; ++j) cc += c_stage[j][t];
        c_lds[t] = cc;
    }
    __syncthreads();
    float sv = (t < FDIM) ? p_lds[t] * r_lds[t] : 0.f;
    #pragma unroll
    for (int off = 32; off >= 1; off >>= 1) sv += __shfl_xor(sv, off);
    if (l == 0) red[w] = sv;
    __syncthreads();
    if (t == 0) { float tt = 0.f; for (int j = 0; j < 16; ++j) tt += red[j]; sc[1] = tt; }
    __syncthreads();
    const float s = sc[1];
    const float4 cc0 = ld4(&c_lds[4 * l]); const float4 cc1 = ld4(&c_lds[256 + 4 * l]);
    float* Ob = S_out + (size_t)b * S_ELEMS;
    for (int j = 31; j >= 0; --j) {
        const int i = j * 16 + w;
        const float* row = Sb + (size_t)i * FDIM;
        float* orow = Ob + (size_t)i * FDIM;
        const float4 a0 = ld4(&row[4 * l]); const float4 a1 = ld4(&row[256 + 4 * l]);
        const float pi = p_lds[i];
        const float f = s - r_lds[i];
        float4 o0, o1;
        o0.x = pi*p0.x*(a0.x + (f - cc0.x)); o0.y = pi*p0.y*(a0.y + (f - cc0.y));
        o0.z = pi*p0.z*(a0.z + (f - cc0.z)); o0.w = pi*p0.w*(a0.w + (f - cc0.w));
        o1.x = pi*p1.x*(a1.x + (f - cc1.x)); o1.y = pi*p1.y*(a1.y + (f - cc1.y));
        o1.z = pi*p1.z*(a1.z + (f - cc1.z)); o1.w = pi*p1.w*(a1.w + (f - cc1.w));
        *(float4*)&orow[4 * l] = o0;
        *(float4*)&orow[256 + 4 * l] = o1;
    }
}

extern "C" void kernel_launch(void* const* d_in, const int* in_sizes, int n_in,
                              void* d_out, int out_size, void* d_ws, size_t ws_size,
                              hipStream_t stream) {
    (void)in_sizes; (void)n_in; (void)out_size;
    const float* mu    = (const float*)d_in[0];
    const float* Sigma = (const float*)d_in[1];
    float* p_out = (float*)d_out;
    float* S_out = (float*)d_out + (size_t)NB * FDIM;

    if (ws_size >= (size_t)WS_FLOATS * sizeof(float)) {
        float* ws = (float*)d_ws;
        for (int g = 0; g < GROUPS; ++g) {
            const int b0 = g * BPG;
            hipLaunchKernelGGL(k1_kernel,  dim3(GBLK), dim3(256), 0, stream,
                               mu, Sigma, p_out, ws, b0);
            hipLaunchKernelGGL(k2b_kernel, dim3(BPG),  dim3(512), 0, stream,
                               p_out, ws, b0);
            hipLaunchKernelGGL(k3_kernel,  dim3(GBLK), dim3(256), 0, stream,
                               Sigma, p_out, ws, S_out, b0);
        }
    } else {
        hipLaunchKernelGGL(rvsoftmax_fused, dim3(NB), dim3(1024), 0, stream,
                           mu, Sigma, p_out, S_out);
    }
}

// Round 12
// 134.100 us; speedup vs baseline: 1.0782x; 1.0782x over previous
//
#include <hip/hip_runtime.h>
#include <hip/hip_fp16.h>

#define FDIM 512
#define S_ELEMS (FDIM * FDIM)
#define NB 256
#define SLABS 8                      // 64-row slabs
#define NBLK (NB * SLABS)            // 2048 blocks per pass

// ---------------- ws layout (floats) ----------------
#define R_OFF  0                               // r[256][512]
#define C_OFF  131072                          // c[256][512]
#define S_OFF  262144                          // s[256]
#define CP_OFF 262400                          // c_part[256*8][512]
#define H_OFF  (CP_OFF + NB * SLABS * FDIM)    // fp16 Sigma copy (as halves)
#define WS_FLOATS (H_OFF + NB * S_ELEMS / 2)   // 67.1M halves = 33.55M floats

__device__ __forceinline__ float4 ld4(const float* p) { return *(const float4*)p; }

typedef float vf4 __attribute__((ext_vector_type(4)));
__device__ __forceinline__ float4 ld4nt(const float* p) {
    vf4 v = __builtin_nontemporal_load((const vf4*)p);
    return *(float4*)&v;
}
__device__ __forceinline__ void st4nt(float* p, float4 v) {
    __builtin_nontemporal_store(*(vf4*)&v, (vf4*)p);
}
__device__ __forceinline__ unsigned pk2(float a, float b) {
    __half2 h = __floats2half2_rn(a, b);
    return *reinterpret_cast<unsigned*>(&h);
}
__device__ __forceinline__ float2 uh2(unsigned u) {
    __half2 h = *reinterpret_cast<__half2*>(&u);
    return __half22float2(h);
}

// ======================= K1: p, r, c-partials + fp16 stage =============
// block = (batch, 64-row slab); 256 thr = 4 waves; 16 rows/wave, 4-deep
// named-register pipeline. NT loads on Sigma (read-once, keep out of L3);
// fp16 copy stored NORMALLY (cacheable 128 MB working set for K3).
__global__ __launch_bounds__(256)
void k1_kernel(const float* __restrict__ mu,
               const float* __restrict__ Sigma,
               float* __restrict__ p_out,
               float* __restrict__ ws) {
    const int bid  = blockIdx.x;
    const int b    = bid >> 3;
    const int slab = bid & 7;
    const int t = threadIdx.x;
    const int w = t >> 6;
    const int l = t & 63;

    __shared__ __align__(16) float p_lds[FDIM];
    __shared__ __align__(16) float cred[4][FDIM];
    __shared__ float red[4];
    __shared__ float sc1;

    // --- softmax p[b,:], 2 elems/thread ---
    const float x0 = mu[(size_t)b * FDIM + t];
    const float x1 = mu[(size_t)b * FDIM + t + 256];
    float m = fmaxf(x0, x1);
    #pragma unroll
    for (int off = 32; off >= 1; off >>= 1) m = fmaxf(m, __shfl_xor(m, off));
    if (l == 0) red[w] = m;
    __syncthreads();
    if (t == 0) sc1 = fmaxf(fmaxf(red[0], red[1]), fmaxf(red[2], red[3]));
    __syncthreads();
    const float mx = sc1;
    const float e0 = __expf(x0 - mx);
    const float e1 = __expf(x1 - mx);
    float ssum = e0 + e1;
    #pragma unroll
    for (int off = 32; off >= 1; off >>= 1) ssum += __shfl_xor(ssum, off);
    if (l == 0) red[w] = ssum;
    __syncthreads();
    if (t == 0) sc1 = red[0] + red[1] + red[2] + red[3];
    __syncthreads();
    const float inv = 1.0f / sc1;
    const float pva = e0 * inv, pvb = e1 * inv;
    p_lds[t] = pva;
    p_lds[t + 256] = pvb;
    if (slab == 0) {
        p_out[(size_t)b * FDIM + t] = pva;
        p_out[(size_t)b * FDIM + t + 256] = pvb;
    }
    __syncthreads();

    const float4 p0 = ld4(&p_lds[4 * l]);
    const float4 p1 = ld4(&p_lds[256 + 4 * l]);

    const int i0 = slab * 64 + w * 16;
    const float* base = Sigma + (size_t)b * S_ELEMS + (size_t)i0 * FDIM + 4 * l;
    float* r_ws = ws + R_OFF + (size_t)b * FDIM;
    __half* h_base = (__half*)(ws + H_OFF) + (size_t)b * S_ELEMS
                   + (size_t)i0 * FDIM + 8 * l;

    float4 c0 = make_float4(0.f, 0.f, 0.f, 0.f);
    float4 c1 = make_float4(0.f, 0.f, 0.f, 0.f);
    float4 A0, A1, B0, B1, C0, C1, D0, D1;

#define LD1(P, q) do { const float* gp_ = base + (size_t)(q) * FDIM;        \
    P##0 = ld4nt(gp_); P##1 = ld4nt(gp_ + 256); } while (0)

#define RCROW(v0, v1, q) do {                                               \
    const int i_ = i0 + (q);                                                \
    float dot = v0.x*p0.x + v0.y*p0.y + v0.z*p0.z + v0.w*p0.w               \
              + v1.x*p1.x + v1.y*p1.y + v1.z*p1.z + v1.w*p1.w;              \
    _Pragma("unroll")                                                       \
    for (int o_ = 32; o_ >= 1; o_ >>= 1) dot += __shfl_xor(dot, o_);        \
    if (l == 0) r_ws[i_] = dot;                                             \
    const float pi_ = p_lds[i_];                                            \
    c0.x += pi_*v0.x; c0.y += pi_*v0.y; c0.z += pi_*v0.z; c0.w += pi_*v0.w; \
    c1.x += pi_*v1.x; c1.y += pi_*v1.y; c1.z += pi_*v1.z; c1.w += pi_*v1.w; \
    uint4 hu_;                                                              \
    hu_.x = pk2(v0.x, v0.y); hu_.y = pk2(v0.z, v0.w);                       \
    hu_.z = pk2(v1.x, v1.y); hu_.w = pk2(v1.z, v1.w);                       \
    *(uint4*)(h_base + (size_t)(q) * FDIM) = hu_;                           \
} while (0)
#define RC1(P, q) RCROW(P##0, P##1, q)

    LD1(A, 0); LD1(B, 1); LD1(C, 2);
    RC1(A, 0);  LD1(D, 3);
    RC1(B, 1);  LD1(A, 4);
    RC1(C, 2);  LD1(B, 5);
    RC1(D, 3);  LD1(C, 6);
    RC1(A, 4);  LD1(D, 7);
    RC1(B, 5);  LD1(A, 8);
    RC1(C, 6);  LD1(B, 9);
    RC1(D, 7);  LD1(C, 10);
    RC1(A, 8);  LD1(D, 11);
    RC1(B, 9);  LD1(A, 12);
    RC1(C, 10); LD1(B, 13);
    RC1(D, 11); LD1(C, 14);
    RC1(A, 12); LD1(D, 15);
    RC1(B, 13);
    RC1(C, 14);
    RC1(D, 15);
#undef LD1
#undef RCROW
#undef RC1

    // --- reduce c partials across the 4 waves ---
    *(float4*)&cred[w][4 * l] = c0;
    *(float4*)&cred[w][256 + 4 * l] = c1;
    __syncthreads();
    const float ca = cred[0][t] + cred[1][t] + cred[2][t] + cred[3][t];
    const float cb = cred[0][t + 256] + cred[1][t + 256] + cred[2][t + 256] + cred[3][t + 256];
    float* cp = ws + CP_OFF + ((size_t)b * SLABS + slab) * FDIM;
    cp[t] = ca;
    cp[t + 256] = cb;
}

// ======================= K2b: final c + s =======================
__global__ __launch_bounds__(512)
void k2b_kernel(const float* __restrict__ p_out, float* __restrict__ ws) {
    const int b = blockIdx.x;
    const int t = threadIdx.x;
    const int w = t >> 6;
    const int l = t & 63;
    __shared__ float red[8];

    float cc = 0.f;
    #pragma unroll
    for (int j = 0; j < SLABS; ++j)
        cc += ws[CP_OFF + ((size_t)b * SLABS + j) * FDIM + t];
    ws[C_OFF + (size_t)b * FDIM + t] = cc;

    float sv = p_out[(size_t)b * FDIM + t] * ws[R_OFF + (size_t)b * FDIM + t];
    #pragma unroll
    for (int off = 32; off >= 1; off >>= 1) sv += __shfl_xor(sv, off);
    if (l == 0) red[w] = sv;
    __syncthreads();
    if (t == 0) {
        float tt = 0.f;
        for (int j = 0; j < 8; ++j) tt += red[j];
        ws[S_OFF + b] = tt;
    }
}

// ======================= K3: fp16 read + NT output stream ==============
// grid 2048 REVERSED (freshest fp16 lines first); 16 rows/wave, 4-deep.
__global__ __launch_bounds__(256)
void k3_kernel(const float* __restrict__ p_out,
               const float* __restrict__ ws,
               float* __restrict__ S_out) {
    const int bid  = NBLK - 1 - (int)blockIdx.x;
    const int b    = bid >> 3;
    const int slab = bid & 7;
    const int t = threadIdx.x;
    const int w = t >> 6;
    const int l = t & 63;

    __shared__ float pr[64], rr[64];

    const int i0 = slab * 64 + w * 16;
    const __half* hb = (const __half*)(ws + H_OFF) + (size_t)b * S_ELEMS
                     + (size_t)i0 * FDIM + 8 * l;
    float* obase = S_out + (size_t)b * S_ELEMS + (size_t)i0 * FDIM + 4 * l;

    uint4 UA, UB, UC, UD;

#define LD3(U, q) U = *(const uint4*)(hb + (size_t)(q) * FDIM)

    // Issue first three rows; they fly during the prologue.
    LD3(UA, 0); LD3(UB, 1); LD3(UC, 2);

    const float* pb_g = p_out + (size_t)b * FDIM;
    const float* rb_g = ws + R_OFF + (size_t)b * FDIM;
    if (t < 64) {
        pr[t] = pb_g[slab * 64 + t];
        rr[t] = rb_g[slab * 64 + t];
    }
    const float  s  = ws[S_OFF + b];
    const float4 p0 = ld4(pb_g + 4 * l);
    const float4 p1 = ld4(pb_g + 256 + 4 * l);
    const float4 c0 = ld4(ws + C_OFF + (size_t)b * FDIM + 4 * l);
    const float4 c1 = ld4(ws + C_OFF + (size_t)b * FDIM + 256 + 4 * l);
    __syncthreads();

#define OWROW(U, q) do {                                                    \
    const float2 f0_ = uh2(U.x), f1_ = uh2(U.y);                            \
    const float2 f2_ = uh2(U.z), f3_ = uh2(U.w);                            \
    const int lr_ = w * 16 + (q);                                           \
    const float pi_ = pr[lr_];                                              \
    const float f_  = s - rr[lr_];                                          \
    float4 o0, o1;                                                          \
    o0.x = pi_*p0.x*(f0_.x + (f_ - c0.x));                                  \
    o0.y = pi_*p0.y*(f0_.y + (f_ - c0.y));                                  \
    o0.z = pi_*p0.z*(f1_.x + (f_ - c0.z));                                  \
    o0.w = pi_*p0.w*(f1_.y + (f_ - c0.w));                                  \
    o1.x = pi_*p1.x*(f2_.x + (f_ - c1.x));                                  \
    o1.y = pi_*p1.y*(f2_.y + (f_ - c1.y));                                  \
    o1.z = pi_*p1.z*(f3_.x + (f_ - c1.z));                                  \
    o1.w = pi_*p1.w*(f3_.y + (f_ - c1.w));                                  \
    float* op_ = obase + (size_t)(q) * FDIM;                                \
    st4nt(op_, o0); st4nt(op_ + 256, o1);                                   \
} while (0)

    OWROW(UA, 0);  LD3(UD, 3);
    OWROW(UB, 1);  LD3(UA, 4);
    OWROW(UC, 2);  LD3(UB, 5);
    OWROW(UD, 3);  LD3(UC, 6);
    OWROW(UA, 4);  LD3(UD, 7);
    OWROW(UB, 5);  LD3(UA, 8);
    OWROW(UC, 6);  LD3(UB, 9);
    OWROW(UD, 7);  LD3(UC, 10);
    OWROW(UA, 8);  LD3(UD, 11);
    OWROW(UB, 9);  LD3(UA, 12);
    OWROW(UC, 10); LD3(UB, 13);
    OWROW(UD, 11); LD3(UC, 14);
    OWROW(UA, 12); LD3(UD, 15);
    OWROW(UB, 13);
    OWROW(UC, 14);
    OWROW(UD, 15);
#undef LD3
#undef OWROW
}

// ======================= fallback: round-1 fused (proven) ========
__global__ __launch_bounds__(1024, 1)
void rvsoftmax_fused(const float* __restrict__ mu,
                     const float* __restrict__ Sigma,
                     float* __restrict__ p_out,
                     float* __restrict__ S_out) {
    const int b = blockIdx.x, t = threadIdx.x, w = t >> 6, l = t & 63;
    __shared__ __align__(16) float p_lds[FDIM];
    __shared__ __align__(16) float r_lds[FDIM];
    __shared__ __align__(16) float c_lds[FDIM];
    __shared__ __align__(16) float c_stage[16][FDIM];
    __shared__ float red[16]; __shared__ float sc[2];
    float x = (t < FDIM) ? mu[(size_t)b * FDIM + t] : -__builtin_inff();
    float m = x;
    #pragma unroll
    for (int off = 32; off >= 1; off >>= 1) m = fmaxf(m, __shfl_xor(m, off));
    if (l == 0) red[w] = m;
    __syncthreads();
    if (t == 0) { float mm = red[0]; for (int j = 1; j < 16; ++j) mm = fmaxf(mm, red[j]); sc[0] = mm; }
    __syncthreads();
    const float mx = sc[0];
    float e = (t < FDIM) ? __expf(x - mx) : 0.f;
    float ssum = e;
    #pragma unroll
    for (int off = 32; off >= 1; off >>= 1) ssum += __shfl_xor(ssum, off);
    if (l == 0) red[w] = ssum;
    __syncthreads();
    if (t == 0) { float tt = 0.f; for (int j = 0; j < 16; ++j) tt += red[j]; sc[0] = tt; }
    __syncthreads();
    const float inv = 1.0f / sc[0];
    if (t < FDIM) { float pv = e * inv; p_lds[t] = pv; p_out[(size_t)b * FDIM + t] = pv; }
    __syncthreads();
    const float* Sb = Sigma + (size_t)b * S_ELEMS;
    const float4 p0 = ld4(&p_lds[4 * l]);
    const float4 p1 = ld4(&p_lds[256 + 4 * l]);
    float4 c0 = make_float4(0.f, 0.f, 0.f, 0.f), c1 = make_float4(0.f, 0.f, 0.f, 0.f);
    for (int j = 0; j < 32; ++j) {
        const int i = j * 16 + w;
        const float* row = Sb + (size_t)i * FDIM;
        const float4 a0 = ld4(&row[4 * l]); const float4 a1 = ld4(&row[256 + 4 * l]);
        const float pi = p_lds[i];
        float dot = a0.x*p0.x + a0.y*p0.y + a0.z*p0.z + a0.w*p0.w
                  + a1.x*p1.x + a1.y*p1.y + a1.z*p1.z + a1.w*p1.w;
        #pragma unroll
        for (int off = 32; off >= 1; off >>= 1) dot += __shfl_xor(dot, off);
        if (l == 0) r_lds[i] = dot;
        c0.x += pi*a0.x; c0.y += pi*a0.y; c0.z += pi*a0.z; c0.w += pi*a0.w;
        c1.x += pi*a1.x; c1.y += pi*a1.y; c1.z += pi*a1.z; c1.w += pi*a1.w;
    }
    *(float4*)&c_stage[w][4 * l] = c0;
    *(float4*)&c_stage[w][256 + 4 * l] = c1;
    __syncthreads();
    if (t < FDIM) {
        float cc = 0.f;
        #pragma unroll
        for (int j = 0; j < 16; ++j) cc += c_stage[j][t];
        c_lds[t] = cc;
    }
    __syncthreads();
    float sv = (t < FDIM) ? p_lds[t] * r_lds[t] : 0.f;
    #pragma unroll
    for (int off = 32; off >= 1; off >>= 1) sv += __shfl_xor(sv, off);
    if (l == 0) red[w] = sv;
    __syncthreads();
    if (t == 0) { float tt = 0.f; for (int j = 0; j < 16; ++j) tt += red[j]; sc[1] = tt; }
    __syncthreads();
    const float s = sc[1];
    const float4 cc0 = ld4(&c_lds[4 * l]); const float4 cc1 = ld4(&c_lds[256 + 4 * l]);
    float* Ob = S_out + (size_t)b * S_ELEMS;
    for (int j = 31; j >= 0; --j) {
        const int i = j * 16 + w;
        const float* row = Sb + (size_t)i * FDIM;
        float* orow = Ob + (size_t)i * FDIM;
        const float4 a0 = ld4(&row[4 * l]); const float4 a1 = ld4(&row[256 + 4 * l]);
        const float pi = p_lds[i];
        const float f = s - r_lds[i];
        float4 o0, o1;
        o0.x = pi*p0.x*(a0.x + (f - cc0.x)); o0.y = pi*p0.y*(a0.y + (f - cc0.y));
        o0.z = pi*p0.z*(a0.z + (f - cc0.z)); o0.w = pi*p0.w*(a0.w + (f - cc0.w));
        o1.x = pi*p1.x*(a1.x + (f - cc1.x)); o1.y = pi*p1.y*(a1.y + (f - cc1.y));
        o1.z = pi*p1.z*(a1.z + (f - cc1.z)); o1.w = pi*p1.w*(a1.w + (f - cc1.w));
        *(float4*)&orow[4 * l] = o0;
        *(float4*)&orow[256 + 4 * l] = o1;
    }
}

extern "C" void kernel_launch(void* const* d_in, const int* in_sizes, int n_in,
                              void* d_out, int out_size, void* d_ws, size_t ws_size,
                              hipStream_t stream) {
    (void)in_sizes; (void)n_in; (void)out_size;
    const float* mu    = (const float*)d_in[0];
    const float* Sigma = (const float*)d_in[1];
    float* p_out = (float*)d_out;
    float* S_out = (float*)d_out + (size_t)NB * FDIM;

    if (ws_size >= (size_t)WS_FLOATS * sizeof(float)) {
        float* ws = (float*)d_ws;
        hipLaunchKernelGGL(k1_kernel,  dim3(NBLK), dim3(256), 0, stream,
                           mu, Sigma, p_out, ws);
        hipLaunchKernelGGL(k2b_kernel, dim3(NB),   dim3(512), 0, stream,
                           p_out, ws);
        hipLaunchKernelGGL(k3_kernel,  dim3(NBLK), dim3(256), 0, stream,
                           p_out, ws, S_out);
    } else {
        hipLaunchKernelGGL(rvsoftmax_fused, dim3(NB), dim3(1024), 0, stream,
                           mu, Sigma, p_out, S_out);
    }
}

// Round 13
// 116.205 us; speedup vs baseline: 1.2442x; 1.1540x over previous
//
#include <hip/hip_runtime.h>

#define FDIM 512
#define S_ELEMS (FDIM * FDIM)
#define NB 256
#define SLABS 8                      // 64-row slabs
#define NBLK (NB * SLABS)            // 2048 blocks per pass

// ---------------- ws layout (floats) ----------------
#define R_OFF  0                               // r[256][512]
#define C_OFF  131072                          // c[256][512]
#define S_OFF  262144                          // s[256]
#define CP_OFF 262400                          // c_part[256*8][512]
#define H_OFF  (CP_OFF + NB * SLABS * FDIM)    // fp8 Sigma copy (1 B/elem)
#define WS_FLOATS (H_OFF + NB * S_ELEMS / 4)   // 67.1M bytes = 16.8M floats

__device__ __forceinline__ float4 ld4(const float* p) { return *(const float4*)p; }

typedef float vf4 __attribute__((ext_vector_type(4)));
typedef float vf2 __attribute__((ext_vector_type(2)));
__device__ __forceinline__ float4 ld4nt(const float* p) {
    vf4 v = __builtin_nontemporal_load((const vf4*)p);
    return *(float4*)&v;
}
__device__ __forceinline__ void st4nt(float* p, float4 v) {
    __builtin_nontemporal_store(*(vf4*)&v, (vf4*)p);
}

// pack 4 floats -> 4 e4m3 bytes (one u32) via HW packed converts
__device__ __forceinline__ unsigned pk8(float a, float b, float c, float d) {
    int u = 0;
    u = __builtin_amdgcn_cvt_pk_fp8_f32(a, b, u, false);  // bytes 0,1
    u = __builtin_amdgcn_cvt_pk_fp8_f32(c, d, u, true);   // bytes 2,3
    return (unsigned)u;
}
// unpack u32 (4 e4m3) -> float4
__device__ __forceinline__ float4 upk8(unsigned u) {
    vf2 lo = __builtin_amdgcn_cvt_pk_f32_fp8((int)u, false);
    vf2 hi = __builtin_amdgcn_cvt_pk_f32_fp8((int)u, true);
    return make_float4(lo.x, lo.y, hi.x, hi.y);
}

// ======================= K1: p, r, c-partials + fp8 stage ==============
// block = (batch, 64-row slab); 256 thr = 4 waves; 16 rows/wave, 4-deep
// named-register pipeline. NT loads on Sigma (read-once, keep out of L3);
// fp8 copy stored NORMALLY (cacheable 64 MB working set for K3).
__global__ __launch_bounds__(256)
void k1_kernel(const float* __restrict__ mu,
               const float* __restrict__ Sigma,
               float* __restrict__ p_out,
               float* __restrict__ ws) {
    const int bid  = blockIdx.x;
    const int b    = bid >> 3;
    const int slab = bid & 7;
    const int t = threadIdx.x;
    const int w = t >> 6;
    const int l = t & 63;

    __shared__ __align__(16) float p_lds[FDIM];
    __shared__ __align__(16) float cred[4][FDIM];
    __shared__ float red[4];
    __shared__ float sc1;

    // --- softmax p[b,:], 2 elems/thread ---
    const float x0 = mu[(size_t)b * FDIM + t];
    const float x1 = mu[(size_t)b * FDIM + t + 256];
    float m = fmaxf(x0, x1);
    #pragma unroll
    for (int off = 32; off >= 1; off >>= 1) m = fmaxf(m, __shfl_xor(m, off));
    if (l == 0) red[w] = m;
    __syncthreads();
    if (t == 0) sc1 = fmaxf(fmaxf(red[0], red[1]), fmaxf(red[2], red[3]));
    __syncthreads();
    const float mx = sc1;
    const float e0 = __expf(x0 - mx);
    const float e1 = __expf(x1 - mx);
    float ssum = e0 + e1;
    #pragma unroll
    for (int off = 32; off >= 1; off >>= 1) ssum += __shfl_xor(ssum, off);
    if (l == 0) red[w] = ssum;
    __syncthreads();
    if (t == 0) sc1 = red[0] + red[1] + red[2] + red[3];
    __syncthreads();
    const float inv = 1.0f / sc1;
    const float pva = e0 * inv, pvb = e1 * inv;
    p_lds[t] = pva;
    p_lds[t + 256] = pvb;
    if (slab == 0) {
        p_out[(size_t)b * FDIM + t] = pva;
        p_out[(size_t)b * FDIM + t + 256] = pvb;
    }
    __syncthreads();

    const float4 p0 = ld4(&p_lds[4 * l]);
    const float4 p1 = ld4(&p_lds[256 + 4 * l]);

    const int i0 = slab * 64 + w * 16;
    const float* base = Sigma + (size_t)b * S_ELEMS + (size_t)i0 * FDIM + 4 * l;
    float* r_ws = ws + R_OFF + (size_t)b * FDIM;
    unsigned char* h_base = (unsigned char*)(ws + H_OFF) + (size_t)b * S_ELEMS
                          + (size_t)i0 * FDIM + 8 * l;   // fp8 row stride 512 B

    float4 c0 = make_float4(0.f, 0.f, 0.f, 0.f);
    float4 c1 = make_float4(0.f, 0.f, 0.f, 0.f);
    float4 A0, A1, B0, B1, C0, C1, D0, D1;

#define LD1(P, q) do { const float* gp_ = base + (size_t)(q) * FDIM;        \
    P##0 = ld4nt(gp_); P##1 = ld4nt(gp_ + 256); } while (0)

#define RCROW(v0, v1, q) do {                                               \
    const int i_ = i0 + (q);                                                \
    float dot = v0.x*p0.x + v0.y*p0.y + v0.z*p0.z + v0.w*p0.w               \
              + v1.x*p1.x + v1.y*p1.y + v1.z*p1.z + v1.w*p1.w;              \
    _Pragma("unroll")                                                       \
    for (int o_ = 32; o_ >= 1; o_ >>= 1) dot += __shfl_xor(dot, o_);        \
    if (l == 0) r_ws[i_] = dot;                                             \
    const float pi_ = p_lds[i_];                                            \
    c0.x += pi_*v0.x; c0.y += pi_*v0.y; c0.z += pi_*v0.z; c0.w += pi_*v0.w; \
    c1.x += pi_*v1.x; c1.y += pi_*v1.y; c1.z += pi_*v1.z; c1.w += pi_*v1.w; \
    uint2 hu_;                                                              \
    hu_.x = pk8(v0.x, v0.y, v0.z, v0.w);                                    \
    hu_.y = pk8(v1.x, v1.y, v1.z, v1.w);                                    \
    *(uint2*)(h_base + (size_t)(q) * FDIM) = hu_;                           \
} while (0)
#define RC1(P, q) RCROW(P##0, P##1, q)

    LD1(A, 0); LD1(B, 1); LD1(C, 2);
    RC1(A, 0);  LD1(D, 3);
    RC1(B, 1);  LD1(A, 4);
    RC1(C, 2);  LD1(B, 5);
    RC1(D, 3);  LD1(C, 6);
    RC1(A, 4);  LD1(D, 7);
    RC1(B, 5);  LD1(A, 8);
    RC1(C, 6);  LD1(B, 9);
    RC1(D, 7);  LD1(C, 10);
    RC1(A, 8);  LD1(D, 11);
    RC1(B, 9);  LD1(A, 12);
    RC1(C, 10); LD1(B, 13);
    RC1(D, 11); LD1(C, 14);
    RC1(A, 12); LD1(D, 15);
    RC1(B, 13);
    RC1(C, 14);
    RC1(D, 15);
#undef LD1
#undef RCROW
#undef RC1

    // --- reduce c partials across the 4 waves ---
    *(float4*)&cred[w][4 * l] = c0;
    *(float4*)&cred[w][256 + 4 * l] = c1;
    __syncthreads();
    const float ca = cred[0][t] + cred[1][t] + cred[2][t] + cred[3][t];
    const float cb = cred[0][t + 256] + cred[1][t + 256] + cred[2][t + 256] + cred[3][t + 256];
    float* cp = ws + CP_OFF + ((size_t)b * SLABS + slab) * FDIM;
    cp[t] = ca;
    cp[t + 256] = cb;
}

// ======================= K2b: final c + s =======================
__global__ __launch_bounds__(512)
void k2b_kernel(const float* __restrict__ p_out, float* __restrict__ ws) {
    const int b = blockIdx.x;
    const int t = threadIdx.x;
    const int w = t >> 6;
    const int l = t & 63;
    __shared__ float red[8];

    float cc = 0.f;
    #pragma unroll
    for (int j = 0; j < SLABS; ++j)
        cc += ws[CP_OFF + ((size_t)b * SLABS + j) * FDIM + t];
    ws[C_OFF + (size_t)b * FDIM + t] = cc;

    float sv = p_out[(size_t)b * FDIM + t] * ws[R_OFF + (size_t)b * FDIM + t];
    #pragma unroll
    for (int off = 32; off >= 1; off >>= 1) sv += __shfl_xor(sv, off);
    if (l == 0) red[w] = sv;
    __syncthreads();
    if (t == 0) {
        float tt = 0.f;
        for (int j = 0; j < 8; ++j) tt += red[j];
        ws[S_OFF + b] = tt;
    }
}

// ======================= K3: fp8 read + NT output stream ===============
// grid 2048 REVERSED (freshest fp8 lines first); 16 rows/wave, 4-deep.
__global__ __launch_bounds__(256)
void k3_kernel(const float* __restrict__ p_out,
               const float* __restrict__ ws,
               float* __restrict__ S_out) {
    const int bid  = NBLK - 1 - (int)blockIdx.x;
    const int b    = bid >> 3;
    const int slab = bid & 7;
    const int t = threadIdx.x;
    const int w = t >> 6;
    const int l = t & 63;

    __shared__ float pr[64], rr[64];

    const int i0 = slab * 64 + w * 16;
    const unsigned char* hb = (const unsigned char*)(ws + H_OFF)
                            + (size_t)b * S_ELEMS + (size_t)i0 * FDIM + 8 * l;
    float* obase = S_out + (size_t)b * S_ELEMS + (size_t)i0 * FDIM + 4 * l;

    uint2 UA, UB, UC, UD;

#define LD3(U, q) U = *(const uint2*)(hb + (size_t)(q) * FDIM)

    // Issue first three rows; they fly during the prologue.
    LD3(UA, 0); LD3(UB, 1); LD3(UC, 2);

    const float* pb_g = p_out + (size_t)b * FDIM;
    const float* rb_g = ws + R_OFF + (size_t)b * FDIM;
    if (t < 64) {
        pr[t] = pb_g[slab * 64 + t];
        rr[t] = rb_g[slab * 64 + t];
    }
    const float  s  = ws[S_OFF + b];
    const float4 p0 = ld4(pb_g + 4 * l);
    const float4 p1 = ld4(pb_g + 256 + 4 * l);
    const float4 c0 = ld4(ws + C_OFF + (size_t)b * FDIM + 4 * l);
    const float4 c1 = ld4(ws + C_OFF + (size_t)b * FDIM + 256 + 4 * l);
    __syncthreads();

#define OWROW(U, q) do {                                                    \
    const float4 fA_ = upk8(U.x);                                           \
    const float4 fB_ = upk8(U.y);                                           \
    const int lr_ = w * 16 + (q);                                           \
    const float pi_ = pr[lr_];                                              \
    const float f_  = s - rr[lr_];                                          \
    float4 o0, o1;                                                          \
    o0.x = pi_*p0.x*(fA_.x + (f_ - c0.x));                                  \
    o0.y = pi_*p0.y*(fA_.y + (f_ - c0.y));                                  \
    o0.z = pi_*p0.z*(fA_.z + (f_ - c0.z));                                  \
    o0.w = pi_*p0.w*(fA_.w + (f_ - c0.w));                                  \
    o1.x = pi_*p1.x*(fB_.x + (f_ - c1.x));                                  \
    o1.y = pi_*p1.y*(fB_.y + (f_ - c1.y));                                  \
    o1.z = pi_*p1.z*(fB_.z + (f_ - c1.z));                                  \
    o1.w = pi_*p1.w*(fB_.w + (f_ - c1.w));                                  \
    float* op_ = obase + (size_t)(q) * FDIM;                                \
    st4nt(op_, o0); st4nt(op_ + 256, o1);                                   \
} while (0)

    OWROW(UA, 0);  LD3(UD, 3);
    OWROW(UB, 1);  LD3(UA, 4);
    OWROW(UC, 2);  LD3(UB, 5);
    OWROW(UD, 3);  LD3(UC, 6);
    OWROW(UA, 4);  LD3(UD, 7);
    OWROW(UB, 5);  LD3(UA, 8);
    OWROW(UC, 6);  LD3(UB, 9);
    OWROW(UD, 7);  LD3(UC, 10);
    OWROW(UA, 8);  LD3(UD, 11);
    OWROW(UB, 9);  LD3(UA, 12);
    OWROW(UC, 10); LD3(UB, 13);
    OWROW(UD, 11); LD3(UC, 14);
    OWROW(UA, 12); LD3(UD, 15);
    OWROW(UB, 13);
    OWROW(UC, 14);
    OWROW(UD, 15);
#undef LD3
#undef OWROW
}

// ======================= fallback: round-1 fused (proven) ========
__global__ __launch_bounds__(1024, 1)
void rvsoftmax_fused(const float* __restrict__ mu,
                     const float* __restrict__ Sigma,
                     float* __restrict__ p_out,
                     float* __restrict__ S_out) {
    const int b = blockIdx.x, t = threadIdx.x, w = t >> 6, l = t & 63;
    __shared__ __align__(16) float p_lds[FDIM];
    __shared__ __align__(16) float r_lds[FDIM];
    __shared__ __align__(16) float c_lds[FDIM];
    __shared__ __align__(16) float c_stage[16][FDIM];
    __shared__ float red[16]; __shared__ float sc[2];
    float x = (t < FDIM) ? mu[(size_t)b * FDIM + t] : -__builtin_inff();
    float m = x;
    #pragma unroll
    for (int off = 32; off >= 1; off >>= 1) m = fmaxf(m, __shfl_xor(m, off));
    if (l == 0) red[w] = m;
    __syncthreads();
    if (t == 0) { float mm = red[0]; for (int j = 1; j < 16; ++j) mm = fmaxf(mm, red[j]); sc[0] = mm; }
    __syncthreads();
    const float mx = sc[0];
    float e = (t < FDIM) ? __expf(x - mx) : 0.f;
    float ssum = e;
    #pragma unroll
    for (int off = 32; off >= 1; off >>= 1) ssum += __shfl_xor(ssum, off);
    if (l == 0) red[w] = ssum;
    __syncthreads();
    if (t == 0) { float tt = 0.f; for (int j = 0; j < 16; ++j) tt += red[j]; sc[0] = tt; }
    __syncthreads();
    const float inv = 1.0f / sc[0];
    if (t < FDIM) { float pv = e * inv; p_lds[t] = pv; p_out[(size_t)b * FDIM + t] = pv; }
    __syncthreads();
    const float* Sb = Sigma + (size_t)b * S_ELEMS;
    const float4 p0 = ld4(&p_lds[4 * l]);
    const float4 p1 = ld4(&p_lds[256 + 4 * l]);
    float4 c0 = make_float4(0.f, 0.f, 0.f, 0.f), c1 = make_float4(0.f, 0.f, 0.f, 0.f);
    for (int j = 0; j < 32; ++j) {
        const int i = j * 16 + w;
        const float* row = Sb + (size_t)i * FDIM;
        const float4 a0 = ld4(&row[4 * l]); const float4 a1 = ld4(&row[256 + 4 * l]);
        const float pi = p_lds[i];
        float dot = a0.x*p0.x + a0.y*p0.y + a0.z*p0.z + a0.w*p0.w
                  + a1.x*p1.x + a1.y*p1.y + a1.z*p1.z + a1.w*p1.w;
        #pragma unroll
        for (int off = 32; off >= 1; off >>= 1) dot += __shfl_xor(dot, off);
        if (l == 0) r_lds[i] = dot;
        c0.x += pi*a0.x; c0.y += pi*a0.y; c0.z += pi*a0.z; c0.w += pi*a0.w;
        c1.x += pi*a1.x; c1.y += pi*a1.y; c1.z += pi*a1.z; c1.w += pi*a1.w;
    }
    *(float4*)&c_stage[w][4 * l] = c0;
    *(float4*)&c_stage[w][256 + 4 * l] = c1;
    __syncthreads();
    if (t < FDIM) {
        float cc = 0.f;
        #pragma unroll
        for (int j = 0; j < 16; ++j) cc += c_stage[j][t];
        c_lds[t] = cc;
    }
    __syncthreads();
    float sv = (t < FDIM) ? p_lds[t] * r_lds[t] : 0.f;
    #pragma unroll
    for (int off = 32; off >= 1; off >>= 1) sv += __shfl_xor(sv, off);
    if (l == 0) red[w] = sv;
    __syncthreads();
    if (t == 0) { float tt = 0.f; for (int j = 0; j < 16; ++j) tt += red[j]; sc[1] = tt; }
    __syncthreads();
    const float s = sc[1];
    const float4 cc0 = ld4(&c_lds[4 * l]); const float4 cc1 = ld4(&c_lds[256 + 4 * l]);
    float* Ob = S_out + (size_t)b * S_ELEMS;
    for (int j = 31; j >= 0; --j) {
        const int i = j * 16 + w;
        const float* row = Sb + (size_t)i * FDIM;
        float* orow = Ob + (size_t)i * FDIM;
        const float4 a0 = ld4(&row[4 * l]); const float4 a1 = ld4(&row[256 + 4 * l]);
        const float pi = p_lds[i];
        const float f = s - r_lds[i];
        float4 o0, o1;
        o0.x = pi*p0.x*(a0.x + (f - cc0.x)); o0.y = pi*p0.y*(a0.y + (f - cc0.y));
        o0.z = pi*p0.z*(a0.z + (f - cc0.z)); o0.w = pi*p0.w*(a0.w + (f - cc0.w));
        o1.x = pi*p1.x*(a1.x + (f - cc1.x)); o1.y = pi*p1.y*(a1.y + (f - cc1.y));
        o1.z = pi*p1.z*(a1.z + (f - cc1.z)); o1.w = pi*p1.w*(a1.w + (f - cc1.w));
        *(float4*)&orow[4 * l] = o0;
        *(float4*)&orow[256 + 4 * l] = o1;
    }
}

extern "C" void kernel_launch(void* const* d_in, const int* in_sizes, int n_in,
                              void* d_out, int out_size, void* d_ws, size_t ws_size,
                              hipStream_t stream) {
    (void)in_sizes; (void)n_in; (void)out_size;
    const float* mu    = (const float*)d_in[0];
    const float* Sigma = (const float*)d_in[1];
    float* p_out = (float*)d_out;
    float* S_out = (float*)d_out + (size_t)NB * FDIM;

    if (ws_size >= (size_t)WS_FLOATS * sizeof(float)) {
        float* ws = (float*)d_ws;
        hipLaunchKernelGGL(k1_kernel,  dim3(NBLK), dim3(256), 0, stream,
                           mu, Sigma, p_out, ws);
        hipLaunchKernelGGL(k2b_kernel, dim3(NB),   dim3(512), 0, stream,
                           p_out, ws);
        hipLaunchKernelGGL(k3_kernel,  dim3(NBLK), dim3(256), 0, stream,
                           p_out, ws, S_out);
    } else {
        hipLaunchKernelGGL(rvsoftmax_fused, dim3(NB), dim3(1024), 0, stream,
                           mu, Sigma, p_out, S_out);
    }
}